// Round 11
// baseline (213.223 us; speedup 1.0000x reference)
//
#include <hip/hip_runtime.h>

#define T_DIM 256
#define B_DIM 256
#define I_DIM 256
#define H_DIM 256
#define COMB  512
#define JCH   16     // j-chunks per gate in the fold (32 columns each)
#define DEPTH 8      // scan software-pipeline depth
#define CHUNK 8      // scan: output steps per parallel-in-time chunk
#define WARM  16     // warm-up steps (empirically bit-exact vs WARM=48)
#define NCH   (T_DIM / CHUNK)   // 32 chunks
#define REPS  32                // write replicas per chunk; each owns 8 b's
#define PGRID 2048              // fused kernel blocks (each produces 32 A-rows)
#define CGRID 1024              // first 1024 blocks also consume (scan+write)

typedef float f32x4 __attribute__((ext_vector_type(4)));

// ws layout (float offsets)
#define OFF_W    0                 // [4][256] FINAL x-part effective weights
#define OFF_PS   1024              // [4][8] sigma partials (h-part j-chunks)
#define OFF_BETA 1056              // [4] beta
#define OFF_A    1152              // [T*B][4] gate pre-activations
#define OFF_CNT  (OFF_A + T_DIM * B_DIM * 4)  // [256] uint per-t progress

// ---------------------------------------------------------------------------
// Kernel 1: j-major weight fold (unchanged from R10) + zeroing cnt[] (block 1).
// ---------------------------------------------------------------------------
__global__ __launch_bounds__(512) void k_w1(
    const float* W0, const float* Q0, const float* B0, const float* q0,
    const float* W1, const float* Q1, const float* B1, const float* q1,
    const float* W2, const float* Q2, const float* B2, const float* q2,
    const float* W3, const float* Q3, const float* B3, const float* q3,
    float* __restrict__ ws) {
  const float* W[4] = {W0, W1, W2, W3};
  const float* Q[4] = {Q0, Q1, Q2, Q3};
  const float* Bv[4] = {B0, B1, B2, B3};
  const float* qv[4] = {q0, q1, q2, q3};
  const int g = blockIdx.x >> 4, jc = blockIdx.x & (JCH - 1);
  const int tid = threadIdx.x;
  const int jj = tid & 31;      // column within the 32-wide chunk
  const int ks = tid >> 5;      // k-subset 0..15 (16 k's each)
  const int j0 = jc * 32;
  const float* Wg = W[g];
  const float* Qg = Q[g];

  if (blockIdx.x == 1 && tid < 256)
    reinterpret_cast<unsigned int*>(ws + OFF_CNT)[tid] = 0u;

  float acc = 0.f;
#pragma unroll
  for (int kk = 0; kk < 16; ++kk) {
    const int k = ks * 16 + kk;
    acc = fmaf(Qg[k], Wg[(size_t)k * COMB + j0 + jj], acc);
  }

  __shared__ float red[512];
  red[tid] = acc;
  __syncthreads();
  for (int s = 256; s >= 32; s >>= 1) {
    if (tid < s) red[tid] += red[tid + s];
    __syncthreads();
  }

  if (jc < 8) {
    if (tid < 32) ws[OFF_W + g * I_DIM + j0 + tid] = red[tid];
  } else {
    if (tid < 16) red[tid] += red[tid + 16];
    __syncthreads();
    if (tid < 8) red[tid] += red[tid + 8];
    __syncthreads();
    if (tid < 4) red[tid] += red[tid + 4];
    __syncthreads();
    if (tid < 2) red[tid] += red[tid + 2];
    __syncthreads();
    if (tid == 0) ws[OFF_PS + g * 8 + (jc - 8)] = red[0] + red[1];
  }

  if (jc == 0) {
    __syncthreads();
    red[tid] = (tid < H_DIM) ? Qg[tid] * Bv[g][tid] : 0.f;
    __syncthreads();
    for (int s = 256; s > 0; s >>= 1) {
      if (tid < s) red[tid] += red[tid + s];
      __syncthreads();
    }
    if (tid == 0) ws[OFF_BETA + g] = red[0] + qv[g][0];
  }
}

// ---------------------------------------------------------------------------
// Gate activation helpers (poly in u = cos(2*theta); E = (1+u)/2 = cos^2 theta)
// ---------------------------------------------------------------------------
#define C0S 0.6224593312f
#define C1S 0.1175018561f
#define C2S (-0.0071946125f)
#define C3S (-0.0020074354f)
#define C4S 0.0002728000f

#define G0T 0.4621171573f
#define G1T 0.3932238600f
#define G2T (-0.0908577800f)
#define G3T (-0.0117749000f)
#define G4T 0.0102923100f
#define G5T (-0.0008507100f)

__device__ __forceinline__ float poly_sig(float u) {
  return fmaf(u, fmaf(u, fmaf(u, fmaf(u, C4S, C3S), C2S), C1S), C0S);
}
__device__ __forceinline__ float poly_tanhE(float u) {
  return fmaf(u, fmaf(u, fmaf(u, fmaf(u, fmaf(u, G5T, G4T), G3T), G2T), G1T), G0T);
}
__device__ __forceinline__ float pade_tanh(float x) {
  const float y = x * x;
  const float num = fmaf(y, fmaf(y, 1.0f, 105.0f), 945.0f);
  const float den = fmaf(y, fmaf(y, 15.0f, 420.0f), 945.0f);
  return x * num * __builtin_amdgcn_rcpf(den);
}

// ---------------------------------------------------------------------------
// Kernel 2 (fused producer-consumer):
//  PRODUCE (all 2048 blocks): block bid computes A rows [bid*32, bid*32+32),
//   all within timestep t = bid>>3 (8 blocks per t). Publish: syncthreads,
//   tid0 threadfence (L2 writeback) + release atomicAdd(cnt[t]).
//  CONSUME (blocks 0..1023): chunk c = bid>>5, replica rep = bid&31. tid0
//   spins (s_sleep-throttled, relaxed loads) until cnt[t]==8 for all t in the
//   chunk's window, threadfence (L2 invalidate), syncthreads; then the
//   parallel-in-time scan + fused H-broadcast nontemporal writes.
//  No-deadlock: produce never waits; >=5 blocks/CU co-residency (launch
//  bounds) => capacity 1280 > 1024 spinners, producers always cycle.
// ---------------------------------------------------------------------------
__global__ __launch_bounds__(256, 5) void k_fused(const float* __restrict__ x,
                                                  float* __restrict__ ws,
                                                  float* __restrict__ out) {
  const int bid = blockIdx.x, tid = threadIdx.x;
  const int wave = tid >> 6, lane = tid & 63;

  __shared__ float wx[4 * I_DIM];
  __shared__ float lds_h[CHUNK][B_DIM];
  __shared__ float lds_hc[2][B_DIM];

  // ---- produce: weights to LDS, 32 rows of A ----
#pragma unroll
  for (int e = 0; e < 4; ++e) wx[tid + e * 256] = ws[OFF_W + tid + e * 256];
  __syncthreads();

  {
    const float bb0 = ws[OFF_BETA + 0], bb1 = ws[OFF_BETA + 1];
    const float bb2 = ws[OFF_BETA + 2], bb3 = ws[OFF_BETA + 3];
    const float4* wx4 = reinterpret_cast<const float4*>(wx);
    const float4 w0 = wx4[0 * 64 + lane];
    const float4 w1 = wx4[1 * 64 + lane];
    const float4 w2 = wx4[2 * 64 + lane];
    const float4 w3 = wx4[3 * 64 + lane];
    const int tP = bid >> 3, bgrp = bid & 7;
    float4* A4o = reinterpret_cast<float4*>(ws + OFF_A);
#pragma unroll
    for (int r = 0; r < 8; ++r) {
      const int b = bgrp * 32 + wave * 8 + r;
      const int row = tP * 256 + b;
      const f32x4 xv = __builtin_nontemporal_load(
          reinterpret_cast<const f32x4*>(x + (size_t)row * I_DIM) + lane);
      float p0 = xv.x * w0.x + xv.y * w0.y + xv.z * w0.z + xv.w * w0.w;
      float p1 = xv.x * w1.x + xv.y * w1.y + xv.z * w1.z + xv.w * w1.w;
      float p2 = xv.x * w2.x + xv.y * w2.y + xv.z * w2.z + xv.w * w2.w;
      float p3 = xv.x * w3.x + xv.y * w3.y + xv.z * w3.z + xv.w * w3.w;
#pragma unroll
      for (int off = 32; off > 0; off >>= 1) {
        p0 += __shfl_down(p0, off, 64);
        p1 += __shfl_down(p1, off, 64);
        p2 += __shfl_down(p2, off, 64);
        p3 += __shfl_down(p3, off, 64);
      }
      if (lane == 0) {
        float4 rr = {2.f * (p0 + bb0), 2.f * (p1 + bb1), 2.f * (p2 + bb2),
                     2.f * (p3 + bb3)};
        A4o[row] = rr;
      }
    }
    __syncthreads();
    unsigned int* cnt = reinterpret_cast<unsigned int*>(ws + OFF_CNT);
    if (tid == 0) {
      __threadfence();  // writeback: A rows -> device scope
      __hip_atomic_fetch_add(&cnt[tP], 1u, __ATOMIC_RELEASE,
                             __HIP_MEMORY_SCOPE_AGENT);
    }
  }

  if (bid >= CGRID) return;

  // ---- consume: chunk scan + broadcast ----
  const int c = bid >> 5;            // chunk 0..31 (ascending: data-ready order)
  const int rep = bid & (REPS - 1);  // owns b in [rep*8, rep*8+8)
  const int b = tid;
  const int t0 = c * CHUNK;
  const int w0c = (t0 - WARM > 0) ? (t0 - WARM) : 0;
  const int NS = t0 + CHUNK - w0c;   // 8, 16, or 24: multiples of DEPTH

  {
    unsigned int* cnt = reinterpret_cast<unsigned int*>(ws + OFF_CNT);
    if (tid == 0) {
      for (int t = w0c; t < t0 + CHUNK; ++t)
        while (__hip_atomic_load(&cnt[t], __ATOMIC_RELAXED,
                                 __HIP_MEMORY_SCOPE_AGENT) != 8u)
          __builtin_amdgcn_s_sleep(8);
      __threadfence();  // acquire: invalidate stale L2 before A reads
    }
    __syncthreads();
  }

  float sg[4];
#pragma unroll
  for (int g = 0; g < 4; ++g) {
    float a = 0.f;
#pragma unroll
    for (int p = 0; p < 8; ++p) a += ws[OFF_PS + g * 8 + p];
    sg[g] = 2.f * a;
  }
  const float s0 = sg[0], s1 = sg[1], s2 = sg[2], s3 = sg[3];

  float C = 0.f, Hs = 0.f;
  const float4* A4 = reinterpret_cast<const float4*>(ws + OFF_A);

  float4 buf[DEPTH];
#pragma unroll
  for (int j = 0; j < DEPTH; ++j) buf[j] = A4[(w0c + j) * B_DIM + b];

#define STEP(a, tt)                                        \
  {                                                        \
    const float uf = __cosf(fmaf(Hs, s0, (a).x));          \
    const float ui = __cosf(fmaf(Hs, s1, (a).y));          \
    const float uu = __cosf(fmaf(Hs, s2, (a).z));          \
    const float uo = __cosf(fmaf(Hs, s3, (a).w));          \
    const float f = poly_sig(uf);                          \
    const float i = poly_sig(ui);                          \
    const float g = poly_tanhE(uu);                        \
    const float o = poly_sig(uo);                          \
    C = fmaf(f, C, i * g);                                 \
    Hs = o * pade_tanh(C);                                 \
    if ((tt) >= t0) lds_h[(tt)-t0][b] = Hs;                \
  }

  for (int sb = 0; sb < NS; sb += DEPTH) {
#pragma unroll
    for (int j = 0; j < DEPTH; ++j) {
      const float4 a = buf[j];
      if (sb + DEPTH + j < NS)
        buf[j] = A4[(w0c + sb + DEPTH + j) * B_DIM + b];  // prefetch
      STEP(a, w0c + sb + j);
    }
  }
#undef STEP

  lds_hc[0][b] = Hs;
  lds_hc[1][b] = C;
  __syncthreads();

  f32x4* o4 = reinterpret_cast<f32x4*>(out);
#pragma unroll
  for (int it = 0; it < 16; ++it) {
    const int idx = it * 256 + tid;   // 0..4095
    const int ts = idx >> 9;          // 0..7
    const int rem = idx & 511;
    const int bb = rem >> 6;          // 0..7
    const int f4 = rem & 63;
    const float v = lds_h[ts][rep * 8 + bb];
    const f32x4 r = {v, v, v, v};
    __builtin_nontemporal_store(
        r, o4 + ((size_t)((t0 + ts) * B_DIM + rep * 8 + bb)) * 64 + f4);
  }
  if (c == NCH - 1) {
    const size_t N1 = (size_t)T_DIM * B_DIM * (H_DIM / 4);
#pragma unroll
    for (int it = 0; it < 2; ++it) {
      const int idx = it * 256 + tid;  // 0..511
      const int bb = idx >> 6;
      const int f4 = idx & 63;
      const float vh = lds_hc[0][rep * 8 + bb];
      const float vc = lds_hc[1][rep * 8 + bb];
      const f32x4 rh = {vh, vh, vh, vh};
      const f32x4 rc = {vc, vc, vc, vc};
      __builtin_nontemporal_store(rh,
                                  o4 + N1 + ((size_t)(rep * 8 + bb)) * 64 + f4);
      __builtin_nontemporal_store(
          rc, o4 + N1 + B_DIM * 64 + ((size_t)(rep * 8 + bb)) * 64 + f4);
    }
  }
}

extern "C" void kernel_launch(void* const* d_in, const int* in_sizes, int n_in,
                              void* d_out, int out_size, void* d_ws,
                              size_t ws_size, hipStream_t stream) {
  const float* x = (const float*)d_in[0];
  const float* Wf = (const float*)d_in[1];
  const float* bf = (const float*)d_in[2];
  const float* Wfq = (const float*)d_in[3];
  const float* bfq = (const float*)d_in[4];
  const float* Wi = (const float*)d_in[5];
  const float* bi = (const float*)d_in[6];
  const float* Wiq = (const float*)d_in[7];
  const float* biq = (const float*)d_in[8];
  const float* Wu = (const float*)d_in[9];
  const float* bu = (const float*)d_in[10];
  const float* Wuq = (const float*)d_in[11];
  const float* buq = (const float*)d_in[12];
  const float* Wo = (const float*)d_in[13];
  const float* bo = (const float*)d_in[14];
  const float* Woq = (const float*)d_in[15];
  const float* boq = (const float*)d_in[16];

  float* ws = (float*)d_ws;
  float* out = (float*)d_out;

  k_w1<<<4 * JCH, 512, 0, stream>>>(Wf, Wfq, bf, bfq, Wi, Wiq, bi, biq, Wu,
                                    Wuq, bu, buq, Wo, Woq, bo, boq, ws);
  k_fused<<<PGRID, 256, 0, stream>>>(x, ws, out);
}